// Round 2
// baseline (276.234 us; speedup 1.0000x reference)
//
#include <hip/hip_runtime.h>
#include <hip/hip_bf16.h>

// QuantLinearAWQ: out[T,N] = x[T,K] @ ((q - z) * s)[K,N] + bias[N]
// T=32, K=4096, N=11008, group=128.
// R9/R10 (math-identical reorders of R8) fail with DIFFERENT small absmax ->
// schedule-dependent corruption from hoisted-register pipelining; that style
// is banned. R8's straight loop is the trusted core.
// R12 (2x occupancy via in-block k-split): NULL (+0.9us) -> GEMM is already
// HBM-BW-bound, not latency-bound. Timed window = 2x ~108us harness poison
// fills (688 MB each, untouchable) + ~50us of our pipeline. qweight traffic
// floor: 180 MB once = 28.6us @ 6.3 TB/s.
// R13: strip pipeline overhead. (a) cvt kernel fused into GEMM: a-frags load
// x fp32 and convert in-register with the same (_Float16) RTN cast ->
// bit-identical to the old xh path, no xh round-trip, one fewer launch.
// (b) atomic epilogue always (the pre-existing ATOMIC path): init kernel
// preloads bias, GEMM unsafeAtomicAdds its k-slice. Drops partials (11.3 MB
// write + 22.6 MB reduce round-trip) and the reduce kernel. 2 launches,
// zero workspace. Inner k-loop body otherwise byte-for-byte R8.

#define TOKENS   32
#define KDIM     4096
#define NDIM     11008
#define GS       128
#define KSPLIT   8
#define KCHUNK   512               // 4 quant groups per k-block
#define BLOCK    256               // 4 waves: (wv_n, wv_k) = (wv&1, wv>>1)
#define BLOCK_N  128               // 86 * 128 == 11008 exactly

typedef __attribute__((ext_vector_type(8))) _Float16 half8;  // MFMA A/B
typedef __attribute__((ext_vector_type(4))) float   floatx4; // MFMA C/D

// ---------- bias preload: out = bias (atomics accumulate on top) ----------
__global__ __launch_bounds__(256) void awq_init_kernel(
    const float* __restrict__ bias, float* __restrict__ out)
{
    const int n = blockIdx.x * 256 + threadIdx.x;      // grid (43, 32)
    out[blockIdx.y * NDIM + n] = bias[n];
}

// ---------- MFMA dequant-GEMM ----------
// A-frag: A[m=lane&15][k=quad*8+j]; C/D: col=lane&15, row=quad*4+reg.
// B symmetric to A. Column remap (R8-verified): MFMA-col c, tile nt ->
// memory column n = nb + 4*c + nt; one int4 per (k-row, lane) feeds 4 tiles.
__global__ __launch_bounds__(BLOCK) void awq_gemm_mfma(
    const float* __restrict__ x,             // [T][K] fp32 (fused cvt)
    const int*   __restrict__ qw,            // [K][N] codes
    const int*   __restrict__ qz,            // [K/GS][N]
    const float* __restrict__ sc,            // [K/GS][N]
    float*       __restrict__ dst)           // out [T][N], bias-preloaded
{
    const int tid  = threadIdx.x;
    const int lane = tid & 63;
    const int wv   = tid >> 6;               // 0..3
    const int wv_n = wv & 1;                 // n-half of the 128-col tile
    const int wv_k = wv >> 1;                // k-half of the 512-row chunk
    const int col  = lane & 15;
    const int quad = lane >> 4;              // 0..3
    const int nb   = blockIdx.x * BLOCK_N + wv_n * 64;
    const int nc   = nb + 4 * col;           // 4 consecutive columns per lane

    // swizzled LDS for the cross-wave k-half combine (2 rowsets x 64 lanes x
    // 8 float4 = 16 KB). Swizzle: float4 slot j stored at (j + lane&7) & 7
    // -> a wave's b128 op spreads across all 8 4-bank groups (BW-floor only).
    __shared__ float4 red[2 * 64 * 8];

    floatx4 acc[4][2];
    #pragma unroll
    for (int nt = 0; nt < 4; ++nt) {
        acc[nt][0] = (floatx4){0.f, 0.f, 0.f, 0.f};
        acc[nt][1] = (floatx4){0.f, 0.f, 0.f, 0.f};
    }

    // outer loop: this wave's 2 quant groups of the k-chunk (plain for-loop,
    // scalar s/z reloads; inner body is the R8 verified loop, with a-frags
    // sourced from fp32 x + in-register RTN cvt instead of the xh buffer)
    for (int gi = 0; gi < KCHUNK / GS / 2; ++gi) {
        const int g   = blockIdx.y * (KCHUNK / GS) + wv_k * (KCHUNK / GS / 2) + gi;
        const int kc0 = g * GS;

        // scalar s/z loads at the remapped columns; (q-8)-(z-8) == q-z
        float s[4], nzs[4];
        #pragma unroll
        for (int nt = 0; nt < 4; ++nt) {
            const int n  = nc + nt;
            const float sv = sc[(size_t)g * NDIM + n];
            const int   zv = qz[(size_t)g * NDIM + n];
            s[nt] = sv; nzs[nt] = -(float)zv * sv;
        }

        const int* qbase = qw + (size_t)(kc0 + quad * 8) * NDIM + nc;
        const float* xr0 = x + (size_t)col * KDIM + kc0 + quad * 8;
        const float* xr1 = xr0 + 16 * KDIM;   // tokens 16-31

        #pragma unroll 2
        for (int ks = 0; ks < GS / 32; ++ks) {   // 4 k-steps of 32
            // 8 x dwordx4: 16B/lane, 256B contiguous per quad-row
            int4 q[8];
            #pragma unroll
            for (int j = 0; j < 8; ++j)
                q[j] = *(const int4*)(qbase + (size_t)(ks * 32 + j) * NDIM);

            // a-frags: fp32 loads (16B aligned: quad*8 floats) + RTN cvt;
            // numerically identical to the old cvt-kernel fp16 path
            const float4 af0 = *(const float4*)(xr0 + ks * 32);
            const float4 af1 = *(const float4*)(xr0 + ks * 32 + 4);
            const float4 ag0 = *(const float4*)(xr1 + ks * 32);
            const float4 ag1 = *(const float4*)(xr1 + ks * 32 + 4);
            half8 a0, a1;
            a0[0] = (_Float16)af0.x; a0[1] = (_Float16)af0.y;
            a0[2] = (_Float16)af0.z; a0[3] = (_Float16)af0.w;
            a0[4] = (_Float16)af1.x; a0[5] = (_Float16)af1.y;
            a0[6] = (_Float16)af1.z; a0[7] = (_Float16)af1.w;
            a1[0] = (_Float16)ag0.x; a1[1] = (_Float16)ag0.y;
            a1[2] = (_Float16)ag0.z; a1[3] = (_Float16)ag0.w;
            a1[4] = (_Float16)ag1.x; a1[5] = (_Float16)ag1.y;
            a1[6] = (_Float16)ag1.z; a1[7] = (_Float16)ag1.w;

            half8 b0, b1, b2, b3;
            #pragma unroll
            for (int j = 0; j < 8; ++j) {
                b0[j] = (_Float16)fmaf((float)q[j].x, s[0], nzs[0]);
                b1[j] = (_Float16)fmaf((float)q[j].y, s[1], nzs[1]);
                b2[j] = (_Float16)fmaf((float)q[j].z, s[2], nzs[2]);
                b3[j] = (_Float16)fmaf((float)q[j].w, s[3], nzs[3]);
            }
            acc[0][0] = __builtin_amdgcn_mfma_f32_16x16x32_f16(a0, b0, acc[0][0], 0, 0, 0);
            acc[0][1] = __builtin_amdgcn_mfma_f32_16x16x32_f16(a1, b0, acc[0][1], 0, 0, 0);
            acc[1][0] = __builtin_amdgcn_mfma_f32_16x16x32_f16(a0, b1, acc[1][0], 0, 0, 0);
            acc[1][1] = __builtin_amdgcn_mfma_f32_16x16x32_f16(a1, b1, acc[1][1], 0, 0, 0);
            acc[2][0] = __builtin_amdgcn_mfma_f32_16x16x32_f16(a0, b2, acc[2][0], 0, 0, 0);
            acc[2][1] = __builtin_amdgcn_mfma_f32_16x16x32_f16(a1, b2, acc[2][1], 0, 0, 0);
            acc[3][0] = __builtin_amdgcn_mfma_f32_16x16x32_f16(a0, b3, acc[3][0], 0, 0, 0);
            acc[3][1] = __builtin_amdgcn_mfma_f32_16x16x32_f16(a1, b3, acc[3][1], 0, 0, 0);
        }
    }

    // ---- cross-wave combine: wv_k==1 publishes, wv_k==0 accumulates ----
    if (wv_k == 1) {
        float4* rp = red + (size_t)(wv_n * 64 + lane) * 8;
        #pragma unroll
        for (int nt = 0; nt < 4; ++nt)
            #pragma unroll
            for (int h = 0; h < 2; ++h) {
                const int js = ((nt * 2 + h) + (lane & 7)) & 7;
                rp[js] = make_float4(acc[nt][h][0], acc[nt][h][1],
                                     acc[nt][h][2], acc[nt][h][3]);
            }
    }
    __syncthreads();
    if (wv_k != 0) return;
    {
        const float4* rp = red + (size_t)(wv_n * 64 + lane) * 8;
        #pragma unroll
        for (int nt = 0; nt < 4; ++nt)
            #pragma unroll
            for (int h = 0; h < 2; ++h) {
                const int js = ((nt * 2 + h) + (lane & 7)) & 7;
                const float4 v = rp[js];
                acc[nt][h][0] += v.x; acc[nt][h][1] += v.y;
                acc[nt][h][2] += v.z; acc[nt][h][3] += v.w;
            }
    }

    // token = h*16 + quad*4 + r; columns nc..nc+3 = tiles 0..3.
    // Atomic accumulate into bias-preloaded out (8 k-slices, commutative).
    #pragma unroll
    for (int h = 0; h < 2; ++h)
        #pragma unroll
        for (int r = 0; r < 4; ++r) {
            float* pp = dst + (size_t)(h * 16 + quad * 4 + r) * NDIM + nc;
            unsafeAtomicAdd(pp + 0, acc[0][h][r]);
            unsafeAtomicAdd(pp + 1, acc[1][h][r]);
            unsafeAtomicAdd(pp + 2, acc[2][h][r]);
            unsafeAtomicAdd(pp + 3, acc[3][h][r]);
        }
}

extern "C" void kernel_launch(void* const* d_in, const int* in_sizes, int n_in,
                              void* d_out, int out_size, void* d_ws, size_t ws_size,
                              hipStream_t stream) {
    const float* x    = (const float*)d_in[0];
    const int*   qw   = (const int*)  d_in[1];
    const int*   qz   = (const int*)  d_in[2];
    const float* sc   = (const float*)d_in[3];
    const float* bias = (const float*)d_in[4];
    float* out = (float*)d_out;
    (void)d_ws; (void)ws_size;   // workspace-free

    awq_init_kernel<<<dim3(NDIM / 256, TOKENS), 256, 0, stream>>>(bias, out);
    awq_gemm_mfma<<<dim3(NDIM / BLOCK_N, KSPLIT), BLOCK, 0, stream>>>(
        x, qw, qz, sc, out);
}

// Round 3
// 264.204 us; speedup vs baseline: 1.0455x; 1.0455x over previous
//
#include <hip/hip_runtime.h>
#include <hip/hip_bf16.h>

// QuantLinearAWQ: out[T,N] = x[T,K] @ ((q - z) * s)[K,N] + bias[N]
// T=32, K=4096, N=11008, group=128.
// R9/R10 (math-identical reorders of R8) fail with DIFFERENT small absmax ->
// schedule-dependent corruption from hoisted-register pipelining; banned.
// R8's straight loop is the trusted core.
// R12 (2x occupancy): NULL -> GEMM is HBM-BW-bound at ~31us (194 MB).
// Timed window = 2x ~107us harness poison fills (704 MB each, fixed-size,
// run even with zero workspace use -> untouchable) + ~50us pipeline.
// R13 (atomic epilogue + fused cvt): -10us REGRESSION, isolated to the
// atomic path: 2.8M f32 atomics with 8-way cross-XCD same-line contention.
// The fused fp32-x a-frag path itself is correctness-verified and
// traffic-neutral (x is L2-resident).
// R14: recombination. R12's epilogue (LDS k-half combine + streamed float4
// partials + reduce kernel) + R13's fp32 a-frag sourcing. Drops the cvt
// kernel: 3 launches -> 2. No atomics on the main path.

#define TOKENS   32
#define KDIM     4096
#define NDIM     11008
#define GS       128
#define KSPLIT   8
#define KCHUNK   512               // 4 quant groups per k-block
#define BLOCK    256               // 4 waves: (wv_n, wv_k) = (wv&1, wv>>1)
#define BLOCK_N  128               // 86 * 128 == 11008 exactly

typedef __attribute__((ext_vector_type(8))) _Float16 half8;  // MFMA A/B
typedef __attribute__((ext_vector_type(4))) float   floatx4; // MFMA C/D

// ---------- bias preload (atomic-fallback path only) ----------
__global__ __launch_bounds__(256) void awq_init_kernel(
    const float* __restrict__ bias, float* __restrict__ out)
{
    const int n = blockIdx.x * 256 + threadIdx.x;      // grid (43, 32)
    out[blockIdx.y * NDIM + n] = bias[n];
}

// ---------- MFMA dequant-GEMM ----------
// A-frag: A[m=lane&15][k=quad*8+j]; C/D: col=lane&15, row=quad*4+reg.
// B symmetric to A. Column remap (R8-verified): MFMA-col c, tile nt ->
// memory column n = nb + 4*c + nt; one int4 per (k-row, lane) feeds 4 tiles.
template<bool ATOMIC>
__global__ __launch_bounds__(BLOCK) void awq_gemm_mfma(
    const float* __restrict__ x,             // [T][K] fp32 (fused cvt)
    const int*   __restrict__ qw,            // [K][N] codes
    const int*   __restrict__ qz,            // [K/GS][N]
    const float* __restrict__ sc,            // [K/GS][N]
    float*       __restrict__ dst)           // part [KSPLIT][T][N] or out [T][N]
{
    const int tid  = threadIdx.x;
    const int lane = tid & 63;
    const int wv   = tid >> 6;               // 0..3
    const int wv_n = wv & 1;                 // n-half of the 128-col tile
    const int wv_k = wv >> 1;                // k-half of the 512-row chunk
    const int col  = lane & 15;
    const int quad = lane >> 4;              // 0..3
    const int nb   = blockIdx.x * BLOCK_N + wv_n * 64;
    const int nc   = nb + 4 * col;           // 4 consecutive columns per lane

    // swizzled LDS for the cross-wave k-half combine (2 rowsets x 64 lanes x
    // 8 float4 = 16 KB). Swizzle: float4 slot j stored at (j + lane&7) & 7
    // -> a wave's b128 op spreads across all 8 4-bank groups (BW-floor only).
    __shared__ float4 red[2 * 64 * 8];

    floatx4 acc[4][2];
    #pragma unroll
    for (int nt = 0; nt < 4; ++nt) {
        acc[nt][0] = (floatx4){0.f, 0.f, 0.f, 0.f};
        acc[nt][1] = (floatx4){0.f, 0.f, 0.f, 0.f};
    }

    // outer loop: this wave's 2 quant groups of the k-chunk (plain for-loop,
    // scalar s/z reloads; inner body is the R8 verified loop, with a-frags
    // sourced from fp32 x + in-register RTN cvt (R13-verified))
    for (int gi = 0; gi < KCHUNK / GS / 2; ++gi) {
        const int g   = blockIdx.y * (KCHUNK / GS) + wv_k * (KCHUNK / GS / 2) + gi;
        const int kc0 = g * GS;

        // scalar s/z loads at the remapped columns; (q-8)-(z-8) == q-z
        float s[4], nzs[4];
        #pragma unroll
        for (int nt = 0; nt < 4; ++nt) {
            const int n  = nc + nt;
            const float sv = sc[(size_t)g * NDIM + n];
            const int   zv = qz[(size_t)g * NDIM + n];
            s[nt] = sv; nzs[nt] = -(float)zv * sv;
        }

        const int* qbase = qw + (size_t)(kc0 + quad * 8) * NDIM + nc;
        const float* xr0 = x + (size_t)col * KDIM + kc0 + quad * 8;
        const float* xr1 = xr0 + 16 * KDIM;   // tokens 16-31

        #pragma unroll 2
        for (int ks = 0; ks < GS / 32; ++ks) {   // 4 k-steps of 32
            // 8 x dwordx4: 16B/lane, 256B contiguous per quad-row
            int4 q[8];
            #pragma unroll
            for (int j = 0; j < 8; ++j)
                q[j] = *(const int4*)(qbase + (size_t)(ks * 32 + j) * NDIM);

            // a-frags: fp32 loads (16B aligned: quad*8 floats) + RTN cvt;
            // numerically identical to the old cvt-kernel fp16 path
            const float4 af0 = *(const float4*)(xr0 + ks * 32);
            const float4 af1 = *(const float4*)(xr0 + ks * 32 + 4);
            const float4 ag0 = *(const float4*)(xr1 + ks * 32);
            const float4 ag1 = *(const float4*)(xr1 + ks * 32 + 4);
            half8 a0, a1;
            a0[0] = (_Float16)af0.x; a0[1] = (_Float16)af0.y;
            a0[2] = (_Float16)af0.z; a0[3] = (_Float16)af0.w;
            a0[4] = (_Float16)af1.x; a0[5] = (_Float16)af1.y;
            a0[6] = (_Float16)af1.z; a0[7] = (_Float16)af1.w;
            a1[0] = (_Float16)ag0.x; a1[1] = (_Float16)ag0.y;
            a1[2] = (_Float16)ag0.z; a1[3] = (_Float16)ag0.w;
            a1[4] = (_Float16)ag1.x; a1[5] = (_Float16)ag1.y;
            a1[6] = (_Float16)ag1.z; a1[7] = (_Float16)ag1.w;

            half8 b0, b1, b2, b3;
            #pragma unroll
            for (int j = 0; j < 8; ++j) {
                b0[j] = (_Float16)fmaf((float)q[j].x, s[0], nzs[0]);
                b1[j] = (_Float16)fmaf((float)q[j].y, s[1], nzs[1]);
                b2[j] = (_Float16)fmaf((float)q[j].z, s[2], nzs[2]);
                b3[j] = (_Float16)fmaf((float)q[j].w, s[3], nzs[3]);
            }
            acc[0][0] = __builtin_amdgcn_mfma_f32_16x16x32_f16(a0, b0, acc[0][0], 0, 0, 0);
            acc[0][1] = __builtin_amdgcn_mfma_f32_16x16x32_f16(a1, b0, acc[0][1], 0, 0, 0);
            acc[1][0] = __builtin_amdgcn_mfma_f32_16x16x32_f16(a0, b1, acc[1][0], 0, 0, 0);
            acc[1][1] = __builtin_amdgcn_mfma_f32_16x16x32_f16(a1, b1, acc[1][1], 0, 0, 0);
            acc[2][0] = __builtin_amdgcn_mfma_f32_16x16x32_f16(a0, b2, acc[2][0], 0, 0, 0);
            acc[2][1] = __builtin_amdgcn_mfma_f32_16x16x32_f16(a1, b2, acc[2][1], 0, 0, 0);
            acc[3][0] = __builtin_amdgcn_mfma_f32_16x16x32_f16(a0, b3, acc[3][0], 0, 0, 0);
            acc[3][1] = __builtin_amdgcn_mfma_f32_16x16x32_f16(a1, b3, acc[3][1], 0, 0, 0);
        }
    }

    // ---- cross-wave combine: wv_k==1 publishes, wv_k==0 accumulates ----
    if (wv_k == 1) {
        float4* rp = red + (size_t)(wv_n * 64 + lane) * 8;
        #pragma unroll
        for (int nt = 0; nt < 4; ++nt)
            #pragma unroll
            for (int h = 0; h < 2; ++h) {
                const int js = ((nt * 2 + h) + (lane & 7)) & 7;
                rp[js] = make_float4(acc[nt][h][0], acc[nt][h][1],
                                     acc[nt][h][2], acc[nt][h][3]);
            }
    }
    __syncthreads();
    if (wv_k != 0) return;
    {
        const float4* rp = red + (size_t)(wv_n * 64 + lane) * 8;
        #pragma unroll
        for (int nt = 0; nt < 4; ++nt)
            #pragma unroll
            for (int h = 0; h < 2; ++h) {
                const int js = ((nt * 2 + h) + (lane & 7)) & 7;
                const float4 v = rp[js];
                acc[nt][h][0] += v.x; acc[nt][h][1] += v.y;
                acc[nt][h][2] += v.z; acc[nt][h][3] += v.w;
            }
    }

    // token = h*16 + quad*4 + r; columns nc..nc+3 = tiles 0..3 -> float4
    if (ATOMIC) {
        #pragma unroll
        for (int h = 0; h < 2; ++h)
            #pragma unroll
            for (int r = 0; r < 4; ++r) {
                float* pp = dst + (size_t)(h * 16 + quad * 4 + r) * NDIM + nc;
                unsafeAtomicAdd(pp + 0, acc[0][h][r]);
                unsafeAtomicAdd(pp + 1, acc[1][h][r]);
                unsafeAtomicAdd(pp + 2, acc[2][h][r]);
                unsafeAtomicAdd(pp + 3, acc[3][h][r]);
            }
    } else {
        float* pbase = dst + (size_t)blockIdx.y * TOKENS * NDIM;
        #pragma unroll
        for (int h = 0; h < 2; ++h)
            #pragma unroll
            for (int r = 0; r < 4; ++r) {
                const float4 v = make_float4(acc[0][h][r], acc[1][h][r],
                                             acc[2][h][r], acc[3][h][r]);
                *(float4*)(pbase + (size_t)(h * 16 + quad * 4 + r) * NDIM + nc) = v;
            }
    }
}

// ---------- reduce KSPLIT partials + bias ----------
__global__ __launch_bounds__(256) void awq_reduce_kernel(
    const float* __restrict__ part,   // [KSPLIT][T][N]
    const float* __restrict__ bias,
    float*       __restrict__ out)    // [T][N]
{
    const int o = blockIdx.x * 256 + threadIdx.x;   // float4 idx, 88064 total
    const int t = o / (NDIM / 4);
    const int c = o - t * (NDIM / 4);
    const float4* p4 = (const float4*)part;
    float4 sum = ((const float4*)bias)[c];
    #pragma unroll
    for (int s = 0; s < KSPLIT; ++s) {
        const float4 v = p4[(size_t)(s * TOKENS + t) * (NDIM / 4) + c];
        sum.x += v.x; sum.y += v.y; sum.z += v.z; sum.w += v.w;
    }
    ((float4*)out)[o] = sum;
}

extern "C" void kernel_launch(void* const* d_in, const int* in_sizes, int n_in,
                              void* d_out, int out_size, void* d_ws, size_t ws_size,
                              hipStream_t stream) {
    const float* x    = (const float*)d_in[0];
    const int*   qw   = (const int*)  d_in[1];
    const int*   qz   = (const int*)  d_in[2];
    const float* sc   = (const float*)d_in[3];
    const float* bias = (const float*)d_in[4];
    float* out = (float*)d_out;

    const size_t part_bytes = (size_t)KSPLIT * TOKENS * NDIM * sizeof(float); // 11.3 MB
    float* part = (float*)d_ws;

    if (ws_size >= part_bytes) {
        awq_gemm_mfma<false><<<dim3(NDIM / BLOCK_N, KSPLIT), BLOCK, 0, stream>>>(
            x, qw, qz, sc, part);
        awq_reduce_kernel<<<(TOKENS * NDIM / 4) / 256, 256, 0, stream>>>(
            part, bias, out);
    } else {
        awq_init_kernel<<<dim3(NDIM / 256, TOKENS), 256, 0, stream>>>(bias, out);
        awq_gemm_mfma<true><<<dim3(NDIM / BLOCK_N, KSPLIT), BLOCK, 0, stream>>>(
            x, qw, qz, sc, out);
    }
}

// Round 5
// 253.201 us; speedup vs baseline: 1.0910x; 1.0435x over previous
//
#include <hip/hip_runtime.h>
#include <hip/hip_bf16.h>

// QuantLinearAWQ: out[T,N] = x[T,K] @ ((q - z) * s)[K,N] + bias[N]
// T=32, K=4096, N=11008, group=128.
// R9/R10 (math-identical reorders of R8) fail with DIFFERENT small absmax ->
// schedule-dependent corruption from hoisted-register pipelining; banned.
// R8's straight loop is the trusted core.
// R12 (2x occupancy): NULL -> GEMM not latency/occupancy-limited.
// R13 (atomic epilogue): -10us regression (8-way cross-XCD line contention).
// R14 (drop cvt, fp32 a-frags): -2.2us. Window = ~214us harness poison fills
// + ~45us GEMM (4.3 TB/s eff. vs 6.3 ceiling) + ~4us reduce + launches.
// R15 theory: the GEMM's ~14us over its 30us BW floor is x-slice re-reads
// (86 n-blocks x 64 KB/slice = 44 MB against a 512 KB array) missing in
// L2/L3 because the 180 MB read-once qweight stream thrashes both. Fix:
// NON-TEMPORAL loads on qweight (evict-first, no-allocate) so the caches
// keep serving x/sc/qz. R15 failed to COMPILE: the builtin rejects HIP's
// int4 wrapper type. R16: identical plan, qweight loaded as a clang
// ext_vector_type(4) int (native vector -> builtin accepts; same
// global_load_dwordx4, same .x/.y/.z/.w element access). Nothing else moved.

#define TOKENS   32
#define KDIM     4096
#define NDIM     11008
#define GS       128
#define KSPLIT   8
#define KCHUNK   512               // 4 quant groups per k-block
#define BLOCK    256               // 4 waves: (wv_n, wv_k) = (wv&1, wv>>1)
#define BLOCK_N  128               // 86 * 128 == 11008 exactly

typedef __attribute__((ext_vector_type(8))) _Float16 half8;  // MFMA A/B
typedef __attribute__((ext_vector_type(4))) float   floatx4; // MFMA C/D
typedef __attribute__((ext_vector_type(4))) int     intx4;   // NT-loadable int4

// ---------- bias preload (atomic-fallback path only) ----------
__global__ __launch_bounds__(256) void awq_init_kernel(
    const float* __restrict__ bias, float* __restrict__ out)
{
    const int n = blockIdx.x * 256 + threadIdx.x;      // grid (43, 32)
    out[blockIdx.y * NDIM + n] = bias[n];
}

// ---------- MFMA dequant-GEMM ----------
// A-frag: A[m=lane&15][k=quad*8+j]; C/D: col=lane&15, row=quad*4+reg.
// B symmetric to A. Column remap (R8-verified): MFMA-col c, tile nt ->
// memory column n = nb + 4*c + nt; one int4 per (k-row, lane) feeds 4 tiles.
template<bool ATOMIC>
__global__ __launch_bounds__(BLOCK) void awq_gemm_mfma(
    const float* __restrict__ x,             // [T][K] fp32 (fused cvt)
    const int*   __restrict__ qw,            // [K][N] codes
    const int*   __restrict__ qz,            // [K/GS][N]
    const float* __restrict__ sc,            // [K/GS][N]
    float*       __restrict__ dst)           // part [KSPLIT][T][N] or out [T][N]
{
    const int tid  = threadIdx.x;
    const int lane = tid & 63;
    const int wv   = tid >> 6;               // 0..3
    const int wv_n = wv & 1;                 // n-half of the 128-col tile
    const int wv_k = wv >> 1;                // k-half of the 512-row chunk
    const int col  = lane & 15;
    const int quad = lane >> 4;              // 0..3
    const int nb   = blockIdx.x * BLOCK_N + wv_n * 64;
    const int nc   = nb + 4 * col;           // 4 consecutive columns per lane

    // swizzled LDS for the cross-wave k-half combine (2 rowsets x 64 lanes x
    // 8 float4 = 16 KB). Swizzle: float4 slot j stored at (j + lane&7) & 7
    // -> a wave's b128 op spreads across all 8 4-bank groups (BW-floor only).
    __shared__ float4 red[2 * 64 * 8];

    floatx4 acc[4][2];
    #pragma unroll
    for (int nt = 0; nt < 4; ++nt) {
        acc[nt][0] = (floatx4){0.f, 0.f, 0.f, 0.f};
        acc[nt][1] = (floatx4){0.f, 0.f, 0.f, 0.f};
    }

    // outer loop: this wave's 2 quant groups of the k-chunk (plain for-loop,
    // scalar s/z reloads; inner body is the R8 verified loop, with a-frags
    // sourced from fp32 x + in-register RTN cvt (R13-verified) and qweight
    // loads marked non-temporal (R16, cache hint only))
    for (int gi = 0; gi < KCHUNK / GS / 2; ++gi) {
        const int g   = blockIdx.y * (KCHUNK / GS) + wv_k * (KCHUNK / GS / 2) + gi;
        const int kc0 = g * GS;

        // scalar s/z loads at the remapped columns; (q-8)-(z-8) == q-z
        float s[4], nzs[4];
        #pragma unroll
        for (int nt = 0; nt < 4; ++nt) {
            const int n  = nc + nt;
            const float sv = sc[(size_t)g * NDIM + n];
            const int   zv = qz[(size_t)g * NDIM + n];
            s[nt] = sv; nzs[nt] = -(float)zv * sv;
        }

        const int* qbase = qw + (size_t)(kc0 + quad * 8) * NDIM + nc;
        const float* xr0 = x + (size_t)col * KDIM + kc0 + quad * 8;
        const float* xr1 = xr0 + 16 * KDIM;   // tokens 16-31

        #pragma unroll 2
        for (int ks = 0; ks < GS / 32; ++ks) {   // 4 k-steps of 32
            // 8 x dwordx4: 16B/lane, 256B contiguous per quad-row.
            // Non-temporal: qweight is read-once (180 MB/iter) -- keep it
            // from evicting the hot x/sc/qz working set in L2/L3.
            intx4 q[8];
            #pragma unroll
            for (int j = 0; j < 8; ++j)
                q[j] = __builtin_nontemporal_load(
                    (const intx4*)(qbase + (size_t)(ks * 32 + j) * NDIM));

            // a-frags: fp32 loads (16B aligned: quad*8 floats) + RTN cvt;
            // numerically identical to the old cvt-kernel fp16 path
            const float4 af0 = *(const float4*)(xr0 + ks * 32);
            const float4 af1 = *(const float4*)(xr0 + ks * 32 + 4);
            const float4 ag0 = *(const float4*)(xr1 + ks * 32);
            const float4 ag1 = *(const float4*)(xr1 + ks * 32 + 4);
            half8 a0, a1;
            a0[0] = (_Float16)af0.x; a0[1] = (_Float16)af0.y;
            a0[2] = (_Float16)af0.z; a0[3] = (_Float16)af0.w;
            a0[4] = (_Float16)af1.x; a0[5] = (_Float16)af1.y;
            a0[6] = (_Float16)af1.z; a0[7] = (_Float16)af1.w;
            a1[0] = (_Float16)ag0.x; a1[1] = (_Float16)ag0.y;
            a1[2] = (_Float16)ag0.z; a1[3] = (_Float16)ag0.w;
            a1[4] = (_Float16)ag1.x; a1[5] = (_Float16)ag1.y;
            a1[6] = (_Float16)ag1.z; a1[7] = (_Float16)ag1.w;

            half8 b0, b1, b2, b3;
            #pragma unroll
            for (int j = 0; j < 8; ++j) {
                b0[j] = (_Float16)fmaf((float)q[j].x, s[0], nzs[0]);
                b1[j] = (_Float16)fmaf((float)q[j].y, s[1], nzs[1]);
                b2[j] = (_Float16)fmaf((float)q[j].z, s[2], nzs[2]);
                b3[j] = (_Float16)fmaf((float)q[j].w, s[3], nzs[3]);
            }
            acc[0][0] = __builtin_amdgcn_mfma_f32_16x16x32_f16(a0, b0, acc[0][0], 0, 0, 0);
            acc[0][1] = __builtin_amdgcn_mfma_f32_16x16x32_f16(a1, b0, acc[0][1], 0, 0, 0);
            acc[1][0] = __builtin_amdgcn_mfma_f32_16x16x32_f16(a0, b1, acc[1][0], 0, 0, 0);
            acc[1][1] = __builtin_amdgcn_mfma_f32_16x16x32_f16(a1, b1, acc[1][1], 0, 0, 0);
            acc[2][0] = __builtin_amdgcn_mfma_f32_16x16x32_f16(a0, b2, acc[2][0], 0, 0, 0);
            acc[2][1] = __builtin_amdgcn_mfma_f32_16x16x32_f16(a1, b2, acc[2][1], 0, 0, 0);
            acc[3][0] = __builtin_amdgcn_mfma_f32_16x16x32_f16(a0, b3, acc[3][0], 0, 0, 0);
            acc[3][1] = __builtin_amdgcn_mfma_f32_16x16x32_f16(a1, b3, acc[3][1], 0, 0, 0);
        }
    }

    // ---- cross-wave combine: wv_k==1 publishes, wv_k==0 accumulates ----
    if (wv_k == 1) {
        float4* rp = red + (size_t)(wv_n * 64 + lane) * 8;
        #pragma unroll
        for (int nt = 0; nt < 4; ++nt)
            #pragma unroll
            for (int h = 0; h < 2; ++h) {
                const int js = ((nt * 2 + h) + (lane & 7)) & 7;
                rp[js] = make_float4(acc[nt][h][0], acc[nt][h][1],
                                     acc[nt][h][2], acc[nt][h][3]);
            }
    }
    __syncthreads();
    if (wv_k != 0) return;
    {
        const float4* rp = red + (size_t)(wv_n * 64 + lane) * 8;
        #pragma unroll
        for (int nt = 0; nt < 4; ++nt)
            #pragma unroll
            for (int h = 0; h < 2; ++h) {
                const int js = ((nt * 2 + h) + (lane & 7)) & 7;
                const float4 v = rp[js];
                acc[nt][h][0] += v.x; acc[nt][h][1] += v.y;
                acc[nt][h][2] += v.z; acc[nt][h][3] += v.w;
            }
    }

    // token = h*16 + quad*4 + r; columns nc..nc+3 = tiles 0..3 -> float4
    if (ATOMIC) {
        #pragma unroll
        for (int h = 0; h < 2; ++h)
            #pragma unroll
            for (int r = 0; r < 4; ++r) {
                float* pp = dst + (size_t)(h * 16 + quad * 4 + r) * NDIM + nc;
                unsafeAtomicAdd(pp + 0, acc[0][h][r]);
                unsafeAtomicAdd(pp + 1, acc[1][h][r]);
                unsafeAtomicAdd(pp + 2, acc[2][h][r]);
                unsafeAtomicAdd(pp + 3, acc[3][h][r]);
            }
    } else {
        float* pbase = dst + (size_t)blockIdx.y * TOKENS * NDIM;
        #pragma unroll
        for (int h = 0; h < 2; ++h)
            #pragma unroll
            for (int r = 0; r < 4; ++r) {
                const float4 v = make_float4(acc[0][h][r], acc[1][h][r],
                                             acc[2][h][r], acc[3][h][r]);
                *(float4*)(pbase + (size_t)(h * 16 + quad * 4 + r) * NDIM + nc) = v;
            }
    }
}

// ---------- reduce KSPLIT partials + bias ----------
__global__ __launch_bounds__(256) void awq_reduce_kernel(
    const float* __restrict__ part,   // [KSPLIT][T][N]
    const float* __restrict__ bias,
    float*       __restrict__ out)    // [T][N]
{
    const int o = blockIdx.x * 256 + threadIdx.x;   // float4 idx, 88064 total
    const int t = o / (NDIM / 4);
    const int c = o - t * (NDIM / 4);
    const float4* p4 = (const float4*)part;
    float4 sum = ((const float4*)bias)[c];
    #pragma unroll
    for (int s = 0; s < KSPLIT; ++s) {
        const float4 v = p4[(size_t)(s * TOKENS + t) * (NDIM / 4) + c];
        sum.x += v.x; sum.y += v.y; sum.z += v.z; sum.w += v.w;
    }
    ((float4*)out)[o] = sum;
}

extern "C" void kernel_launch(void* const* d_in, const int* in_sizes, int n_in,
                              void* d_out, int out_size, void* d_ws, size_t ws_size,
                              hipStream_t stream) {
    const float* x    = (const float*)d_in[0];
    const int*   qw   = (const int*)  d_in[1];
    const int*   qz   = (const int*)  d_in[2];
    const float* sc   = (const float*)d_in[3];
    const float* bias = (const float*)d_in[4];
    float* out = (float*)d_out;

    const size_t part_bytes = (size_t)KSPLIT * TOKENS * NDIM * sizeof(float); // 11.3 MB
    float* part = (float*)d_ws;

    if (ws_size >= part_bytes) {
        awq_gemm_mfma<false><<<dim3(NDIM / BLOCK_N, KSPLIT), BLOCK, 0, stream>>>(
            x, qw, qz, sc, part);
        awq_reduce_kernel<<<(TOKENS * NDIM / 4) / 256, 256, 0, stream>>>(
            part, bias, out);
    } else {
        awq_init_kernel<<<dim3(NDIM / 256, TOKENS), 256, 0, stream>>>(bias, out);
        awq_gemm_mfma<true><<<dim3(NDIM / BLOCK_N, KSPLIT), BLOCK, 0, stream>>>(
            x, qw, qz, sc, out);
    }
}